// Round 3
// baseline (5027.164 us; speedup 1.0000x reference)
//
#include <hip/hip_runtime.h>
#include <math.h>

#define BB 4
#define NN 2048
#define DD 64
#define PP 8192
#define NSTRIPE 512

__global__ void zero_ws_kernel(float* ws) {
    int t = blockIdx.x * blockDim.x + threadIdx.x;
    if (t < BB * NSTRIPE) ws[t] = 0.f;
}

__device__ __forceinline__ void ce_dir(float& a, float& b, bool up) {
    float lo = fminf(a, b), hi = fmaxf(a, b);
    a = up ? lo : hi;
    b = up ? hi : lo;
}

__device__ __forceinline__ float dot4(float4 a, float4 b) {
    return a.x * b.x + a.y * b.y + a.z * b.z + a.w * b.w;
}

// exchange with lane^LM inside a wave64.
// LM=1,2  : DPP quad_perm xor1/xor2 (VALU pipe)
// LM=8    : DPP row_ror:8 == xor8 within rows of 16 (VALU pipe)
// LM=4,16 : ds_swizzle xor mode (LDS pipe, no bank conflicts)
// LM=32   : bpermute via __shfl_xor (only one pass uses it)
template<int LM>
__device__ __forceinline__ float xorlane(float v) {
    int x = __float_as_int(v), r;
    if constexpr (LM == 1)       r = __builtin_amdgcn_update_dpp(x, x, 0xB1, 0xF, 0xF, false);
    else if constexpr (LM == 2)  r = __builtin_amdgcn_update_dpp(x, x, 0x4E, 0xF, 0xF, false);
    else if constexpr (LM == 4)  r = __builtin_amdgcn_ds_swizzle(x, 0x101F);
    else if constexpr (LM == 8)  r = __builtin_amdgcn_update_dpp(x, x, 0x128, 0xF, 0xF, false);
    else if constexpr (LM == 16) r = __builtin_amdgcn_ds_swizzle(x, 0x401F);
    else                         return __shfl_xor(v, 32, 64);
    return __int_as_float(r);
}

// k = 2..16: all intra-thread, directions compile-time after unroll
__device__ __forceinline__ void phaseA(float* e) {
    #pragma unroll
    for (int k = 2; k <= 16; k <<= 1)
        #pragma unroll
        for (int j = k >> 1; j >= 1; j >>= 1)
            #pragma unroll
            for (int v = 0; v < 32; v++)
                if ((v & j) == 0) ce_dir(e[v], e[v | j], (v & k) == 0);
}

// intra-thread j=16..1 with uniform runtime direction, both arrays interleaved
__device__ __forceinline__ void intra2(float* e1, float* e2, bool up) {
    #pragma unroll
    for (int j = 16; j >= 1; j >>= 1)
        #pragma unroll
        for (int v = 0; v < 32; v++)
            if ((v & j) == 0) {
                ce_dir(e1[v], e1[v | j], up);
                ce_dir(e2[v], e2[v | j], up);
            }
}

template<int LM>
__device__ __forceinline__ void cross(float* e1, float* e2, bool keepmin) {
    #pragma unroll
    for (int v = 0; v < 32; v++) {
        float p = xorlane<LM>(e1[v]);
        e1[v] = keepmin ? fminf(e1[v], p) : fmaxf(e1[v], p);
        float q = xorlane<LM>(e2[v]);
        e2[v] = keepmin ? fminf(e2[v], q) : fmaxf(e2[v], q);
    }
}

template<int LM>
__device__ __forceinline__ void cross_chain(float* e1, float* e2, bool up, int lane) {
    cross<LM>(e1, e2, up == ((lane & LM) == 0));
    if constexpr (LM > 1) cross_chain<(LM >> 1)>(e1, e2, up, lane);
}

template<int K>
__device__ __forceinline__ void merge_level(float* e1, float* e2, int lane) {
    const bool up = (lane & (K >> 5)) == 0;   // for K=2048 this folds to true
    cross_chain<(K >> 6)>(e1, e2, up, lane);
    intra2(e1, e2, up);
}

__global__ __launch_bounds__(256, 4) void swd_kernel(const float* __restrict__ x,
                                                     const float* __restrict__ y,
                                                     const float* __restrict__ proj,
                                                     float* __restrict__ ws) {
    __shared__ float sprj[4 * DD];

    const int tid = threadIdx.x;
    const int lane = tid & 63;
    const int w = tid >> 6;
    const int cp = (blockIdx.x << 2) | w;     // column-pair id, 0..32767
    const int b = cp >> 13;                   // 8192 consecutive cps share x[b],y[b]
    const int p = cp & (PP - 1);

    // stage this wave's projection row (64 floats, coalesced)
    sprj[w * DD + lane] = proj[(size_t)p * DD + lane];
    __syncthreads();

    // ---- projection: lane owns rows lane*32 .. lane*32+31 (element i = lane*32+v)
    float e1[32], e2[32];
    #pragma unroll
    for (int v = 0; v < 32; v++) { e1[v] = 0.f; e2[v] = 0.f; }

    const float* xb = x + (size_t)b * NN * DD + (size_t)lane * 32 * DD;
    const float* yb = y + (size_t)b * NN * DD + (size_t)lane * 32 * DD;
    const float4* sp4 = (const float4*)(sprj + w * DD);

    #pragma unroll 1
    for (int db = 0; db < 4; db++) {          // 16-float chunk of the D axis
        float4 p0 = sp4[db * 4 + 0];
        float4 p1 = sp4[db * 4 + 1];
        float4 p2 = sp4[db * 4 + 2];
        float4 p3 = sp4[db * 4 + 3];
        #pragma unroll
        for (int v = 0; v < 32; v++) {
            const float4* xr = (const float4*)(xb + v * DD + db * 16);
            float4 a0 = xr[0], a1 = xr[1], a2 = xr[2], a3 = xr[3];
            e1[v] += dot4(a0, p0) + dot4(a1, p1) + dot4(a2, p2) + dot4(a3, p3);
            const float4* yr = (const float4*)(yb + v * DD + db * 16);
            float4 b0 = yr[0], b1 = yr[1], b2 = yr[2], b3 = yr[3];
            e2[v] += dot4(b0, p0) + dot4(b1, p1) + dot4(b2, p2) + dot4(b3, p3);
        }
    }

    // ---- bitonic sort, fully wave-local
    phaseA(e1);
    phaseA(e2);
    intra2(e1, e2, (lane & 1) == 0);          // k = 32 (j = 16..1)
    merge_level<64>(e1, e2, lane);
    merge_level<128>(e1, e2, lane);
    merge_level<256>(e1, e2, lane);
    merge_level<512>(e1, e2, lane);
    merge_level<1024>(e1, e2, lane);
    merge_level<2048>(e1, e2, lane);

    // ---- sum of squared diffs (positions already match in-register)
    float s = 0.f;
    #pragma unroll
    for (int v = 0; v < 32; v++) {
        float d = e1[v] - e2[v];
        s += d * d;
    }
    #pragma unroll
    for (int off = 32; off > 0; off >>= 1)
        s += __shfl_down(s, off, 64);
    if (lane == 0)
        atomicAdd(&ws[b * NSTRIPE + (cp & (NSTRIPE - 1))], s);
}

__global__ void finalize_kernel(const float* __restrict__ ws, float* __restrict__ out) {
    __shared__ float red[256];
    int tid = threadIdx.x;
    for (int b = 0; b < BB; b++) {
        float s = 0.f;
        for (int i = tid; i < NSTRIPE; i += 256) s += ws[b * NSTRIPE + i];
        red[tid] = s;
        __syncthreads();
        for (int o = 128; o > 0; o >>= 1) {
            if (tid < o) red[tid] += red[tid + o];
            __syncthreads();
        }
        if (tid == 0) {
            float swd = red[0] / ((float)NN * (float)PP);
            out[b] = expf(-swd * swd * 0.5f);
        }
        __syncthreads();
    }
}

extern "C" void kernel_launch(void* const* d_in, const int* in_sizes, int n_in,
                              void* d_out, int out_size, void* d_ws, size_t ws_size,
                              hipStream_t stream) {
    const float* x = (const float*)d_in[0];
    const float* y = (const float*)d_in[1];
    const float* proj = (const float*)d_in[2];
    float* out = (float*)d_out;
    float* ws = (float*)d_ws;

    zero_ws_kernel<<<(BB * NSTRIPE + 255) / 256, 256, 0, stream>>>(ws);
    swd_kernel<<<BB * PP / 4, 256, 0, stream>>>(x, y, proj, ws);
    finalize_kernel<<<1, 256, 0, stream>>>(ws, out);
}

// Round 4
// 4986.035 us; speedup vs baseline: 1.0082x; 1.0082x over previous
//
#include <hip/hip_runtime.h>
#include <math.h>

#define BB 4
#define NN 2048
#define DD 64
#define PP 8192
#define NSTRIPE 512
#define VV 16          // elements per lane; 128 threads per column-pair

__global__ void zero_ws_kernel(float* ws) {
    int t = blockIdx.x * blockDim.x + threadIdx.x;
    if (t < BB * NSTRIPE) ws[t] = 0.f;
}

__device__ __forceinline__ void ce_dir(float& a, float& b, bool up) {
    float lo = fminf(a, b), hi = fmaxf(a, b);
    a = up ? lo : hi;
    b = up ? hi : lo;
}

// exchange with lane^LM inside a wave64 (verified correct in round 3):
// LM=1,2 : DPP quad_perm ; LM=8 : DPP row_ror:8 ; LM=4,16 : ds_swizzle xor ; LM=32 : shfl
template<int LM>
__device__ __forceinline__ float xorlane(float v) {
    int x = __float_as_int(v), r;
    if constexpr (LM == 1)       r = __builtin_amdgcn_update_dpp(x, x, 0xB1, 0xF, 0xF, false);
    else if constexpr (LM == 2)  r = __builtin_amdgcn_update_dpp(x, x, 0x4E, 0xF, 0xF, false);
    else if constexpr (LM == 4)  r = __builtin_amdgcn_ds_swizzle(x, 0x101F);
    else if constexpr (LM == 8)  r = __builtin_amdgcn_update_dpp(x, x, 0x128, 0xF, 0xF, false);
    else if constexpr (LM == 16) r = __builtin_amdgcn_ds_swizzle(x, 0x401F);
    else                         return __shfl_xor(v, 32, 64);
    return __int_as_float(r);
}

// k = 2,4,8: fully intra-lane, directions depend on v only (compile-time)
__device__ __forceinline__ void phaseA16(float* e) {
    #pragma unroll
    for (int k = 2; k <= 8; k <<= 1)
        #pragma unroll
        for (int j = k >> 1; j >= 1; j >>= 1)
            #pragma unroll
            for (int v = 0; v < VV; v++)
                if ((v & j) == 0) ce_dir(e[v], e[v | j], (v & k) == 0);
}

// intra-lane tail j = 8,4,2,1 with uniform runtime direction, both arrays interleaved
__device__ __forceinline__ void intra16(float* e1, float* e2, bool up) {
    #pragma unroll
    for (int j = 8; j >= 1; j >>= 1)
        #pragma unroll
        for (int v = 0; v < VV; v++)
            if ((v & j) == 0) {
                ce_dir(e1[v], e1[v | j], up);
                ce_dir(e2[v], e2[v | j], up);
            }
}

template<int LM>
__device__ __forceinline__ void cross(float* e1, float* e2, bool keepmin) {
    #pragma unroll
    for (int v = 0; v < VV; v++) {
        float p = xorlane<LM>(e1[v]);
        e1[v] = keepmin ? fminf(e1[v], p) : fmaxf(e1[v], p);
        float q = xorlane<LM>(e2[v]);
        e2[v] = keepmin ? fminf(e2[v], q) : fmaxf(e2[v], q);
    }
}

template<int LM>
__device__ __forceinline__ void cross_chain(float* e1, float* e2, bool up, int tp) {
    cross<LM>(e1, e2, up == ((tp & LM) == 0));
    if constexpr (LM > 1) cross_chain<(LM >> 1)>(e1, e2, up, tp);
}

template<int K>
__device__ __forceinline__ void merge_level(float* e1, float* e2, int tp) {
    const bool up = (tp & (K >> 4)) == 0;
    cross_chain<(K >> 5)>(e1, e2, up, tp);
    intra16(e1, e2, up);
}

__global__ __launch_bounds__(256, 4) void swd_kernel(const float* __restrict__ x,
                                                     const float* __restrict__ y,
                                                     const float* __restrict__ proj,
                                                     float* __restrict__ ws) {
    __shared__ float sb[8192];                 // 32 KB: 2 pairs x 2 arrays x 2048

    const int tid = threadIdx.x;
    const int tp = tid & 127;                  // thread-in-pair
    const int cp = (blockIdx.x << 1) | (tid >> 7);   // column-pair id 0..32767
    const int b = __builtin_amdgcn_readfirstlane(cp >> 13);
    const int p = __builtin_amdgcn_readfirstlane(cp & (PP - 1));

    // ---- projection: lane owns rows tp*16 .. tp*16+15; proj row lives in SGPRs
    float e1[VV], e2[VV];
    #pragma unroll
    for (int v = 0; v < VV; v++) { e1[v] = 0.f; e2[v] = 0.f; }

    const float* prow = proj + (size_t)p * DD;
    const float* xb = x + (size_t)b * NN * DD + (size_t)tp * VV * DD;
    const float* yb = y + (size_t)b * NN * DD + (size_t)tp * VV * DD;

    #pragma unroll 1
    for (int h = 0; h < 2; h++) {              // D in two halves of 32 -> low SGPR+VGPR pressure
        float pr[32];
        #pragma unroll
        for (int d = 0; d < 32; d++)           // force SGPR residency (wave-uniform)
            pr[d] = __int_as_float(__builtin_amdgcn_readfirstlane(__float_as_int(prow[h * 32 + d])));
        #pragma unroll
        for (int v = 0; v < VV; v++) {
            const float4* xr = (const float4*)(xb + v * DD + h * 32);
            float a = 0.f;
            #pragma unroll
            for (int c = 0; c < 8; c++) {
                float4 xv = xr[c];
                a += xv.x * pr[c * 4] + xv.y * pr[c * 4 + 1] + xv.z * pr[c * 4 + 2] + xv.w * pr[c * 4 + 3];
            }
            e1[v] += a;
            const float4* yr = (const float4*)(yb + v * DD + h * 32);
            float bacc = 0.f;
            #pragma unroll
            for (int c = 0; c < 8; c++) {
                float4 yv = yr[c];
                bacc += yv.x * pr[c * 4] + yv.y * pr[c * 4 + 1] + yv.z * pr[c * 4 + 2] + yv.w * pr[c * 4 + 3];
            }
            e2[v] += bacc;
        }
    }

    // ---- bitonic sort: element i = tp*16 + v, ascending over the 2048-column
    phaseA16(e1);
    phaseA16(e2);
    intra16(e1, e2, (tp & 1) == 0);            // k = 16 (j = 8..1, dir = bit0 of tp)
    merge_level<32>(e1, e2, tp);
    merge_level<64>(e1, e2, tp);
    merge_level<128>(e1, e2, tp);
    merge_level<256>(e1, e2, tp);
    merge_level<512>(e1, e2, tp);
    merge_level<1024>(e1, e2, tp);

    // k = 2048: first pass lm = 64 crosses the pair's two waves -> LDS (up = true)
    {
        const int pb = (tid >> 7) << 12;       // pair base: 4096 floats
        #pragma unroll
        for (int v = 0; v < VV; v++) {
            sb[pb + (v << 7) + tp] = e1[v];
            sb[pb + 2048 + (v << 7) + tp] = e2[v];
        }
        __syncthreads();
        const int pt = tp ^ 64;
        const bool keepmin = (tp & 64) == 0;
        #pragma unroll
        for (int v = 0; v < VV; v++) {
            float pv = sb[pb + (v << 7) + pt];
            e1[v] = keepmin ? fminf(e1[v], pv) : fmaxf(e1[v], pv);
            float qv = sb[pb + 2048 + (v << 7) + pt];
            e2[v] = keepmin ? fminf(e2[v], qv) : fmaxf(e2[v], qv);
        }
    }
    cross_chain<32>(e1, e2, true, tp);         // k = 2048 remainder
    intra16(e1, e2, true);

    // ---- sum of squared diffs (positions already match in-register)
    float s = 0.f;
    #pragma unroll
    for (int v = 0; v < VV; v++) {
        float d = e1[v] - e2[v];
        s += d * d;
    }
    #pragma unroll
    for (int off = 32; off > 0; off >>= 1)
        s += __shfl_down(s, off, 64);
    if ((tid & 63) == 0)
        atomicAdd(&ws[b * NSTRIPE + (cp & (NSTRIPE - 1))], s);
}

__global__ void finalize_kernel(const float* __restrict__ ws, float* __restrict__ out) {
    __shared__ float red[256];
    int tid = threadIdx.x;
    for (int b = 0; b < BB; b++) {
        float s = 0.f;
        for (int i = tid; i < NSTRIPE; i += 256) s += ws[b * NSTRIPE + i];
        red[tid] = s;
        __syncthreads();
        for (int o = 128; o > 0; o >>= 1) {
            if (tid < o) red[tid] += red[tid + o];
            __syncthreads();
        }
        if (tid == 0) {
            float swd = red[0] / ((float)NN * (float)PP);
            out[b] = expf(-swd * swd * 0.5f);
        }
        __syncthreads();
    }
}

extern "C" void kernel_launch(void* const* d_in, const int* in_sizes, int n_in,
                              void* d_out, int out_size, void* d_ws, size_t ws_size,
                              hipStream_t stream) {
    const float* x = (const float*)d_in[0];
    const float* y = (const float*)d_in[1];
    const float* proj = (const float*)d_in[2];
    float* out = (float*)d_out;
    float* ws = (float*)d_ws;

    zero_ws_kernel<<<(BB * NSTRIPE + 255) / 256, 256, 0, stream>>>(ws);
    swd_kernel<<<BB * PP / 2, 256, 0, stream>>>(x, y, proj, ws);
    finalize_kernel<<<1, 256, 0, stream>>>(ws, out);
}

// Round 5
// 3594.767 us; speedup vs baseline: 1.3985x; 1.3870x over previous
//
#include <hip/hip_runtime.h>
#include <math.h>

#define BB 4
#define NN 2048
#define DD 64
#define PP 8192
#define NSTRIPE 512
#define VV 16          // elements per lane; 128 threads per column-pair

__global__ void zero_ws_kernel(float* ws) {
    int t = blockIdx.x * blockDim.x + threadIdx.x;
    if (t < BB * NSTRIPE) ws[t] = 0.f;
}

__device__ __forceinline__ void ce_dir(float& a, float& b, bool up) {
    float lo = fminf(a, b), hi = fmaxf(a, b);
    a = up ? lo : hi;
    b = up ? hi : lo;
}

// exchange with lane^LM inside a wave64 (verified correct in rounds 3/4):
// LM=1,2 : DPP quad_perm ; LM=8 : DPP row_ror:8 ; LM=4,16 : ds_swizzle xor ; LM=32 : shfl
template<int LM>
__device__ __forceinline__ float xorlane(float v) {
    int x = __float_as_int(v), r;
    if constexpr (LM == 1)       r = __builtin_amdgcn_update_dpp(x, x, 0xB1, 0xF, 0xF, false);
    else if constexpr (LM == 2)  r = __builtin_amdgcn_update_dpp(x, x, 0x4E, 0xF, 0xF, false);
    else if constexpr (LM == 4)  r = __builtin_amdgcn_ds_swizzle(x, 0x101F);
    else if constexpr (LM == 8)  r = __builtin_amdgcn_update_dpp(x, x, 0x128, 0xF, 0xF, false);
    else if constexpr (LM == 16) r = __builtin_amdgcn_ds_swizzle(x, 0x401F);
    else                         return __shfl_xor(v, 32, 64);
    return __int_as_float(r);
}

// k = 2,4,8: fully intra-lane, directions depend on v only (compile-time)
__device__ __forceinline__ void phaseA16(float* e) {
    #pragma unroll
    for (int k = 2; k <= 8; k <<= 1)
        #pragma unroll
        for (int j = k >> 1; j >= 1; j >>= 1)
            #pragma unroll
            for (int v = 0; v < VV; v++)
                if ((v & j) == 0) ce_dir(e[v], e[v | j], (v & k) == 0);
}

// intra-lane tail j = 8,4,2,1 with uniform runtime direction, both arrays interleaved
__device__ __forceinline__ void intra16(float* e1, float* e2, bool up) {
    #pragma unroll
    for (int j = 8; j >= 1; j >>= 1)
        #pragma unroll
        for (int v = 0; v < VV; v++)
            if ((v & j) == 0) {
                ce_dir(e1[v], e1[v | j], up);
                ce_dir(e2[v], e2[v | j], up);
            }
}

template<int LM>
__device__ __forceinline__ void cross(float* e1, float* e2, bool keepmin) {
    #pragma unroll
    for (int v = 0; v < VV; v++) {
        float p = xorlane<LM>(e1[v]);
        e1[v] = keepmin ? fminf(e1[v], p) : fmaxf(e1[v], p);
        float q = xorlane<LM>(e2[v]);
        e2[v] = keepmin ? fminf(e2[v], q) : fmaxf(e2[v], q);
    }
}

template<int LM>
__device__ __forceinline__ void cross_chain(float* e1, float* e2, bool up, int tp) {
    cross<LM>(e1, e2, up == ((tp & LM) == 0));
    if constexpr (LM > 1) cross_chain<(LM >> 1)>(e1, e2, up, tp);
}

template<int K>
__device__ __forceinline__ void merge_level(float* e1, float* e2, int tp) {
    const bool up = (tp & (K >> 4)) == 0;
    cross_chain<(K >> 5)>(e1, e2, up, tp);
    intra16(e1, e2, up);
}

__global__ __launch_bounds__(256) void swd_kernel(const float* __restrict__ x,
                                                  const float* __restrict__ y,
                                                  const float* __restrict__ proj,
                                                  float* __restrict__ ws) {
    __shared__ float sb[8192];                 // 32 KB: 2 pairs x 2 arrays x 2048

    const int tid = threadIdx.x;
    const int tp = tid & 127;                  // thread-in-pair
    const int cp = (blockIdx.x << 1) | (tid >> 7);   // column-pair id 0..32767
    const int b = __builtin_amdgcn_readfirstlane(cp >> 13);
    const int p = __builtin_amdgcn_readfirstlane(cp & (PP - 1));

    // ---- projection: lane owns rows tp*16 .. tp*16+15; proj row lives in SGPRs
    float e1[VV], e2[VV];
    #pragma unroll
    for (int v = 0; v < VV; v++) { e1[v] = 0.f; e2[v] = 0.f; }

    const float* prow = proj + (size_t)p * DD;
    const float* xb = x + (size_t)b * NN * DD + (size_t)tp * VV * DD;
    const float* yb = y + (size_t)b * NN * DD + (size_t)tp * VV * DD;

    #pragma unroll 1
    for (int h = 0; h < 2; h++) {              // D in two halves of 32 -> low register pressure
        float pr[32];
        #pragma unroll
        for (int d = 0; d < 32; d++)           // force SGPR residency (wave-uniform)
            pr[d] = __int_as_float(__builtin_amdgcn_readfirstlane(__float_as_int(prow[h * 32 + d])));
        #pragma unroll
        for (int v = 0; v < VV; v++) {
            const float4* xr = (const float4*)(xb + v * DD + h * 32);
            float a = 0.f;
            #pragma unroll
            for (int c = 0; c < 8; c++) {
                float4 xv = xr[c];
                a += xv.x * pr[c * 4] + xv.y * pr[c * 4 + 1] + xv.z * pr[c * 4 + 2] + xv.w * pr[c * 4 + 3];
            }
            e1[v] += a;
            const float4* yr = (const float4*)(yb + v * DD + h * 32);
            float bacc = 0.f;
            #pragma unroll
            for (int c = 0; c < 8; c++) {
                float4 yv = yr[c];
                bacc += yv.x * pr[c * 4] + yv.y * pr[c * 4 + 1] + yv.z * pr[c * 4 + 2] + yv.w * pr[c * 4 + 3];
            }
            e2[v] += bacc;
        }
    }

    // ---- bitonic sort: element i = tp*16 + v, ascending over the 2048-column
    phaseA16(e1);
    phaseA16(e2);
    intra16(e1, e2, (tp & 1) == 0);            // k = 16 (j = 8..1, dir = bit0 of tp)
    merge_level<32>(e1, e2, tp);
    merge_level<64>(e1, e2, tp);
    merge_level<128>(e1, e2, tp);
    merge_level<256>(e1, e2, tp);
    merge_level<512>(e1, e2, tp);
    merge_level<1024>(e1, e2, tp);

    // k = 2048: first pass lm = 64 crosses the pair's two waves -> LDS (up = true)
    {
        const int pb = (tid >> 7) << 12;       // pair base: 4096 floats
        #pragma unroll
        for (int v = 0; v < VV; v++) {
            sb[pb + (v << 7) + tp] = e1[v];
            sb[pb + 2048 + (v << 7) + tp] = e2[v];
        }
        __syncthreads();
        const int pt = tp ^ 64;
        const bool keepmin = (tp & 64) == 0;
        #pragma unroll
        for (int v = 0; v < VV; v++) {
            float pv = sb[pb + (v << 7) + pt];
            e1[v] = keepmin ? fminf(e1[v], pv) : fmaxf(e1[v], pv);
            float qv = sb[pb + 2048 + (v << 7) + pt];
            e2[v] = keepmin ? fminf(e2[v], qv) : fmaxf(e2[v], qv);
        }
    }
    cross_chain<32>(e1, e2, true, tp);         // k = 2048 remainder
    intra16(e1, e2, true);

    // ---- sum of squared diffs (positions already match in-register)
    float s = 0.f;
    #pragma unroll
    for (int v = 0; v < VV; v++) {
        float d = e1[v] - e2[v];
        s += d * d;
    }
    #pragma unroll
    for (int off = 32; off > 0; off >>= 1)
        s += __shfl_down(s, off, 64);
    if ((tid & 63) == 0)
        atomicAdd(&ws[b * NSTRIPE + (cp & (NSTRIPE - 1))], s);
}

__global__ void finalize_kernel(const float* __restrict__ ws, float* __restrict__ out) {
    __shared__ float red[256];
    int tid = threadIdx.x;
    for (int b = 0; b < BB; b++) {
        float s = 0.f;
        for (int i = tid; i < NSTRIPE; i += 256) s += ws[b * NSTRIPE + i];
        red[tid] = s;
        __syncthreads();
        for (int o = 128; o > 0; o >>= 1) {
            if (tid < o) red[tid] += red[tid + o];
            __syncthreads();
        }
        if (tid == 0) {
            float swd = red[0] / ((float)NN * (float)PP);
            out[b] = expf(-swd * swd * 0.5f);
        }
        __syncthreads();
    }
}

extern "C" void kernel_launch(void* const* d_in, const int* in_sizes, int n_in,
                              void* d_out, int out_size, void* d_ws, size_t ws_size,
                              hipStream_t stream) {
    const float* x = (const float*)d_in[0];
    const float* y = (const float*)d_in[1];
    const float* proj = (const float*)d_in[2];
    float* out = (float*)d_out;
    float* ws = (float*)d_ws;

    zero_ws_kernel<<<(BB * NSTRIPE + 255) / 256, 256, 0, stream>>>(ws);
    swd_kernel<<<BB * PP / 2, 256, 0, stream>>>(x, y, proj, ws);
    finalize_kernel<<<1, 256, 0, stream>>>(ws, out);
}

// Round 6
// 1244.588 us; speedup vs baseline: 4.0392x; 2.8883x over previous
//
#include <hip/hip_runtime.h>
#include <math.h>

#define BB 4
#define NN 2048
#define DD 64
#define PP 8192
#define NSTRIPE 512
#define VV 16          // elements per lane; 128 threads per column-pair

__global__ void zero_ws_kernel(float* ws) {
    int t = blockIdx.x * blockDim.x + threadIdx.x;
    if (t < BB * NSTRIPE) ws[t] = 0.f;
}

__device__ __forceinline__ void ce_dir(float& a, float& b, bool up) {
    float lo = fminf(a, b), hi = fmaxf(a, b);
    a = up ? lo : hi;
    b = up ? hi : lo;
}

__device__ __forceinline__ float dot4(float4 a, float4 b) {
    return a.x * b.x + a.y * b.y + a.z * b.z + a.w * b.w;
}

// exchange with lane^LM inside a wave64 (verified correct in rounds 3-5):
// LM=1,2 : DPP quad_perm ; LM=8 : DPP row_ror:8 ; LM=4,16 : ds_swizzle xor ; LM=32 : shfl
template<int LM>
__device__ __forceinline__ float xorlane(float v) {
    int x = __float_as_int(v), r;
    if constexpr (LM == 1)       r = __builtin_amdgcn_update_dpp(x, x, 0xB1, 0xF, 0xF, false);
    else if constexpr (LM == 2)  r = __builtin_amdgcn_update_dpp(x, x, 0x4E, 0xF, 0xF, false);
    else if constexpr (LM == 4)  r = __builtin_amdgcn_ds_swizzle(x, 0x101F);
    else if constexpr (LM == 8)  r = __builtin_amdgcn_update_dpp(x, x, 0x128, 0xF, 0xF, false);
    else if constexpr (LM == 16) r = __builtin_amdgcn_ds_swizzle(x, 0x401F);
    else                         return __shfl_xor(v, 32, 64);
    return __int_as_float(r);
}

// k = 2,4,8: fully intra-lane, directions depend on v only (compile-time)
__device__ __forceinline__ void phaseA16(float* e) {
    #pragma unroll
    for (int k = 2; k <= 8; k <<= 1)
        #pragma unroll
        for (int j = k >> 1; j >= 1; j >>= 1)
            #pragma unroll
            for (int v = 0; v < VV; v++)
                if ((v & j) == 0) ce_dir(e[v], e[v | j], (v & k) == 0);
}

// intra-lane tail j = 8,4,2,1 with uniform runtime direction, both arrays interleaved
__device__ __forceinline__ void intra16(float* e1, float* e2, bool up) {
    #pragma unroll
    for (int j = 8; j >= 1; j >>= 1)
        #pragma unroll
        for (int v = 0; v < VV; v++)
            if ((v & j) == 0) {
                ce_dir(e1[v], e1[v | j], up);
                ce_dir(e2[v], e2[v | j], up);
            }
}

template<int LM>
__device__ __forceinline__ void cross(float* e1, float* e2, bool keepmin) {
    #pragma unroll
    for (int v = 0; v < VV; v++) {
        float p = xorlane<LM>(e1[v]);
        e1[v] = keepmin ? fminf(e1[v], p) : fmaxf(e1[v], p);
        float q = xorlane<LM>(e2[v]);
        e2[v] = keepmin ? fminf(e2[v], q) : fmaxf(e2[v], q);
    }
}

template<int LM>
__device__ __forceinline__ void cross_chain(float* e1, float* e2, bool up, int tp) {
    cross<LM>(e1, e2, up == ((tp & LM) == 0));
    if constexpr (LM > 1) cross_chain<(LM >> 1)>(e1, e2, up, tp);
}

template<int K>
__device__ __forceinline__ void merge_level(float* e1, float* e2, int tp) {
    const bool up = (tp & (K >> 4)) == 0;
    cross_chain<(K >> 5)>(e1, e2, up, tp);
    intra16(e1, e2, up);
}

__global__ __launch_bounds__(256) void swd_kernel(const float* __restrict__ x,
                                                  const float* __restrict__ y,
                                                  const float* __restrict__ proj,
                                                  float* __restrict__ ws) {
    __shared__ float sb[8192];                 // 32 KB: per pair 4096 floats (x res | y res)

    const int tid = threadIdx.x;
    const int lane = tid & 63;
    const int tp = tid & 127;                  // thread-in-pair
    const int wInPair = (tid >> 6) & 1;
    const int pairInBlk = tid >> 7;
    const int cp = (blockIdx.x << 1) | pairInBlk;    // column-pair id 0..32767
    const int b = __builtin_amdgcn_readfirstlane(cp >> 13);
    const int p = __builtin_amdgcn_readfirstlane(cp & (PP - 1));
    const int pb = pairInBlk << 12;            // pair's LDS base (4096 floats)

    // ---- cooperative coalesced projection ----
    // lane = r4*4 + c4 : 16 rows per wave-iteration, 4 lanes per row (64B chunk each)
    const int r4 = lane >> 2;
    const int c4 = lane & 3;

    const float4* prow4 = (const float4*)(proj + (size_t)p * DD);
    float4 pj0 = prow4[0 * 4 + c4];            // this lane's dims c4*4.. within each 16-chunk
    float4 pj1 = prow4[1 * 4 + c4];
    float4 pj2 = prow4[2 * 4 + c4];
    float4 pj3 = prow4[3 * 4 + c4];

    const size_t rowb = (size_t)(wInPair * 1024 + r4);   // this lane-group's row at it=0
    const float* xw = x + (size_t)b * NN * DD + rowb * DD + c4 * 4;
    const float* yw = y + (size_t)b * NN * DD + rowb * DD + c4 * 4;

    #pragma unroll 2
    for (int it = 0; it < 64; it++) {          // 16 rows / iteration
        const float* xi = xw + (size_t)it * 16 * DD;
        const float* yi = yw + (size_t)it * 16 * DD;
        float4 v0 = *(const float4*)(xi + 0 * 16);
        float4 v1 = *(const float4*)(xi + 1 * 16);
        float4 v2 = *(const float4*)(xi + 2 * 16);
        float4 v3 = *(const float4*)(xi + 3 * 16);
        float4 u0 = *(const float4*)(yi + 0 * 16);
        float4 u1 = *(const float4*)(yi + 1 * 16);
        float4 u2 = *(const float4*)(yi + 2 * 16);
        float4 u3 = *(const float4*)(yi + 3 * 16);
        float ax = dot4(v0, pj0) + dot4(v1, pj1) + dot4(v2, pj2) + dot4(v3, pj3);
        float ay = dot4(u0, pj0) + dot4(u1, pj1) + dot4(u2, pj2) + dot4(u3, pj3);
        // reduce over the 4-lane group (quad_perm DPP, VALU pipe)
        ax += xorlane<1>(ax); ax += xorlane<2>(ax);
        ay += xorlane<1>(ay); ay += xorlane<2>(ay);
        const int row = wInPair * 1024 + (it << 4) + r4;
        if (c4 == 0) sb[pb + row] = ax;
        if (c4 == 1) sb[pb + 2048 + row] = ay;
    }
    __syncthreads();

    // readback into blocked register layout: element i = tp*16 + v
    float e1[VV], e2[VV];
    {
        const float4* s1 = (const float4*)(sb + pb + tp * VV);
        const float4* s2 = (const float4*)(sb + pb + 2048 + tp * VV);
        #pragma unroll
        for (int vb = 0; vb < 4; vb++) {
            float4 t1 = s1[vb];
            e1[vb * 4 + 0] = t1.x; e1[vb * 4 + 1] = t1.y;
            e1[vb * 4 + 2] = t1.z; e1[vb * 4 + 3] = t1.w;
            float4 t2 = s2[vb];
            e2[vb * 4 + 0] = t2.x; e2[vb * 4 + 1] = t2.y;
            e2[vb * 4 + 2] = t2.z; e2[vb * 4 + 3] = t2.w;
        }
    }
    __syncthreads();                            // sb is reused by the k=2048 exchange below

    // ---- bitonic sort: element i = tp*16 + v, ascending over the 2048-column
    phaseA16(e1);
    phaseA16(e2);
    intra16(e1, e2, (tp & 1) == 0);            // k = 16 (j = 8..1, dir = bit0 of tp)
    merge_level<32>(e1, e2, tp);
    merge_level<64>(e1, e2, tp);
    merge_level<128>(e1, e2, tp);
    merge_level<256>(e1, e2, tp);
    merge_level<512>(e1, e2, tp);
    merge_level<1024>(e1, e2, tp);

    // k = 2048: first pass lm = 64 crosses the pair's two waves -> LDS (up = true)
    {
        #pragma unroll
        for (int v = 0; v < VV; v++) {
            sb[pb + (v << 7) + tp] = e1[v];
            sb[pb + 2048 + (v << 7) + tp] = e2[v];
        }
        __syncthreads();
        const int pt = tp ^ 64;
        const bool keepmin = (tp & 64) == 0;
        #pragma unroll
        for (int v = 0; v < VV; v++) {
            float pv = sb[pb + (v << 7) + pt];
            e1[v] = keepmin ? fminf(e1[v], pv) : fmaxf(e1[v], pv);
            float qv = sb[pb + 2048 + (v << 7) + pt];
            e2[v] = keepmin ? fminf(e2[v], qv) : fmaxf(e2[v], qv);
        }
    }
    cross_chain<32>(e1, e2, true, tp);         // k = 2048 remainder
    intra16(e1, e2, true);

    // ---- sum of squared diffs (positions already match in-register)
    float s = 0.f;
    #pragma unroll
    for (int v = 0; v < VV; v++) {
        float d = e1[v] - e2[v];
        s += d * d;
    }
    #pragma unroll
    for (int off = 32; off > 0; off >>= 1)
        s += __shfl_down(s, off, 64);
    if ((tid & 63) == 0)
        atomicAdd(&ws[b * NSTRIPE + (cp & (NSTRIPE - 1))], s);
}

__global__ void finalize_kernel(const float* __restrict__ ws, float* __restrict__ out) {
    __shared__ float red[256];
    int tid = threadIdx.x;
    for (int b = 0; b < BB; b++) {
        float s = 0.f;
        for (int i = tid; i < NSTRIPE; i += 256) s += ws[b * NSTRIPE + i];
        red[tid] = s;
        __syncthreads();
        for (int o = 128; o > 0; o >>= 1) {
            if (tid < o) red[tid] += red[tid + o];
            __syncthreads();
        }
        if (tid == 0) {
            float swd = red[0] / ((float)NN * (float)PP);
            out[b] = expf(-swd * swd * 0.5f);
        }
        __syncthreads();
    }
}

extern "C" void kernel_launch(void* const* d_in, const int* in_sizes, int n_in,
                              void* d_out, int out_size, void* d_ws, size_t ws_size,
                              hipStream_t stream) {
    const float* x = (const float*)d_in[0];
    const float* y = (const float*)d_in[1];
    const float* proj = (const float*)d_in[2];
    float* out = (float*)d_out;
    float* ws = (float*)d_ws;

    zero_ws_kernel<<<(BB * NSTRIPE + 255) / 256, 256, 0, stream>>>(ws);
    swd_kernel<<<BB * PP / 2, 256, 0, stream>>>(x, y, proj, ws);
    finalize_kernel<<<1, 256, 0, stream>>>(ws, out);
}

// Round 8
// 1173.119 us; speedup vs baseline: 4.2853x; 1.0609x over previous
//
#include <hip/hip_runtime.h>
#include <math.h>

#define BB 4
#define NN 2048
#define DD 64
#define PP 8192
#define NSTRIPE 512
#define VV 16          // packed elements per lane; 128 threads per column-pair

typedef unsigned int u32;
typedef _Float16 h2 __attribute__((ext_vector_type(2)));

__global__ void zero_ws_kernel(float* ws) {
    int t = blockIdx.x * blockDim.x + threadIdx.x;
    if (t < BB * NSTRIPE) ws[t] = 0.f;
}

__device__ __forceinline__ float dot4(float4 a, float4 b) {
    return a.x * b.x + a.y * b.y + a.z * b.z + a.w * b.w;
}

// packed fp16 min/max -> v_pk_min_f16 / v_pk_max_f16
__device__ __forceinline__ u32 pk_min(u32 a, u32 b) {
    h2 r = __builtin_elementwise_min(__builtin_bit_cast(h2, a), __builtin_bit_cast(h2, b));
    return __builtin_bit_cast(u32, r);
}
__device__ __forceinline__ u32 pk_max(u32 a, u32 b) {
    h2 r = __builtin_elementwise_max(__builtin_bit_cast(h2, a), __builtin_bit_cast(h2, b));
    return __builtin_bit_cast(u32, r);
}

// packed CE: both halves (x-col in lo, y-col in hi) sort through the same network
__device__ __forceinline__ void ce2(u32& a, u32& b, bool up) {
    u32 lo = pk_min(a, b), hi = pk_max(a, b);
    a = up ? lo : hi;
    b = up ? hi : lo;
}

// exchange with lane^LM inside a wave64 (verified correct rounds 3-6):
// LM=1,2 : DPP quad_perm ; LM=8 : DPP row_ror:8 ; LM=4,16 : ds_swizzle xor ; LM=32 : shfl
template<int LM>
__device__ __forceinline__ int xorlane_i(int x) {
    if constexpr (LM == 1)       return __builtin_amdgcn_update_dpp(x, x, 0xB1, 0xF, 0xF, false);
    else if constexpr (LM == 2)  return __builtin_amdgcn_update_dpp(x, x, 0x4E, 0xF, 0xF, false);
    else if constexpr (LM == 4)  return __builtin_amdgcn_ds_swizzle(x, 0x101F);
    else if constexpr (LM == 8)  return __builtin_amdgcn_update_dpp(x, x, 0x128, 0xF, 0xF, false);
    else if constexpr (LM == 16) return __builtin_amdgcn_ds_swizzle(x, 0x401F);
    else                         return __shfl_xor(x, 32, 64);
}
template<int LM>
__device__ __forceinline__ float xorlane_f(float v) {
    return __int_as_float(xorlane_i<LM>(__float_as_int(v)));
}

// k = 2,4,8: fully intra-lane, directions depend on v only (compile-time)
__device__ __forceinline__ void phaseA16p(u32* e) {
    #pragma unroll
    for (int k = 2; k <= 8; k <<= 1)
        #pragma unroll
        for (int j = k >> 1; j >= 1; j >>= 1)
            #pragma unroll
            for (int v = 0; v < VV; v++)
                if ((v & j) == 0) ce2(e[v], e[v | j], (v & k) == 0);
}

// intra-lane tail j = 8,4,2,1 with uniform runtime direction
__device__ __forceinline__ void intra16p(u32* e, bool up) {
    #pragma unroll
    for (int j = 8; j >= 1; j >>= 1)
        #pragma unroll
        for (int v = 0; v < VV; v++)
            if ((v & j) == 0) ce2(e[v], e[v | j], up);
}

template<int LM>
__device__ __forceinline__ void crossp(u32* e, bool keepmin) {
    #pragma unroll
    for (int v = 0; v < VV; v++) {
        u32 p = (u32)xorlane_i<LM>((int)e[v]);
        e[v] = keepmin ? pk_min(e[v], p) : pk_max(e[v], p);
    }
}

template<int LM>
__device__ __forceinline__ void cross_chainp(u32* e, bool up, int tp) {
    crossp<LM>(e, up == ((tp & LM) == 0));
    if constexpr (LM > 1) cross_chainp<(LM >> 1)>(e, up, tp);
}

template<int K>
__device__ __forceinline__ void merge_levelp(u32* e, int tp) {
    const bool up = (tp & (K >> 4)) == 0;
    cross_chainp<(K >> 5)>(e, up, tp);
    intra16p(e, up);
}

__global__ __launch_bounds__(256) void swd_kernel(const float* __restrict__ x,
                                                  const float* __restrict__ y,
                                                  const float* __restrict__ proj,
                                                  float* __restrict__ ws) {
    __shared__ __align__(16) u32 sbu[4096];    // 16 KB: 2 pairs x 2048 packed values

    const int tid = threadIdx.x;
    const int lane = tid & 63;
    const int tp = tid & 127;                  // thread-in-pair
    const int wInPair = (tid >> 6) & 1;
    const int pairInBlk = tid >> 7;
    const int cp = (blockIdx.x << 1) | pairInBlk;    // column-pair id 0..32767
    const int b = __builtin_amdgcn_readfirstlane(cp >> 13);
    const int p = __builtin_amdgcn_readfirstlane(cp & (PP - 1));
    const int pbu = pairInBlk << 11;           // pair's LDS base (2048 u32)

    // ---- cooperative coalesced projection ----
    // lane = r4*4 + c4 : 16 rows per wave-iteration, 4 lanes per row (64B chunk each)
    const int r4 = lane >> 2;
    const int c4 = lane & 3;

    const float4* prow4 = (const float4*)(proj + (size_t)p * DD);
    float4 pj0 = prow4[0 * 4 + c4];
    float4 pj1 = prow4[1 * 4 + c4];
    float4 pj2 = prow4[2 * 4 + c4];
    float4 pj3 = prow4[3 * 4 + c4];

    const size_t rowb = (size_t)(wInPair * 1024 + r4);
    const float* xw = x + (size_t)b * NN * DD + rowb * DD + c4 * 4;
    const float* yw = y + (size_t)b * NN * DD + rowb * DD + c4 * 4;

    #pragma unroll 2
    for (int it = 0; it < 64; it++) {          // 16 rows / iteration
        const float* xi = xw + (size_t)it * 16 * DD;
        const float* yi = yw + (size_t)it * 16 * DD;
        float4 v0 = *(const float4*)(xi + 0 * 16);
        float4 v1 = *(const float4*)(xi + 1 * 16);
        float4 v2 = *(const float4*)(xi + 2 * 16);
        float4 v3 = *(const float4*)(xi + 3 * 16);
        float4 u0 = *(const float4*)(yi + 0 * 16);
        float4 u1 = *(const float4*)(yi + 1 * 16);
        float4 u2 = *(const float4*)(yi + 2 * 16);
        float4 u3 = *(const float4*)(yi + 3 * 16);
        float ax = dot4(v0, pj0) + dot4(v1, pj1) + dot4(v2, pj2) + dot4(v3, pj3);
        float ay = dot4(u0, pj0) + dot4(u1, pj1) + dot4(u2, pj2) + dot4(u3, pj3);
        // reduce over the 4-lane group (quad_perm DPP, VALU pipe); all 4 lanes get the sum
        ax += xorlane_f<1>(ax); ax += xorlane_f<2>(ax);
        ay += xorlane_f<1>(ay); ay += xorlane_f<2>(ay);
        if (c4 == 0) {
            const int row = wInPair * 1024 + (it << 4) + r4;
            h2 h = { (_Float16)ax, (_Float16)ay };    // x-col -> lo, y-col -> hi
            sbu[pbu + row] = __builtin_bit_cast(u32, h);
        }
    }
    __syncthreads();

    // readback into blocked register layout: element i = tp*16 + v (packed)
    u32 e[VV];
    {
        const uint4* s4 = (const uint4*)(sbu + pbu + tp * VV);
        #pragma unroll
        for (int vb = 0; vb < 4; vb++) {
            uint4 t = s4[vb];
            e[vb * 4 + 0] = t.x; e[vb * 4 + 1] = t.y;
            e[vb * 4 + 2] = t.z; e[vb * 4 + 3] = t.w;
        }
    }
    __syncthreads();                            // sbu reused by the k=2048 exchange below

    // ---- bitonic sort (both columns at once, packed): element i = tp*16 + v
    phaseA16p(e);
    intra16p(e, (tp & 1) == 0);                // k = 16 (j = 8..1, dir = bit0 of tp)
    merge_levelp<32>(e, tp);
    merge_levelp<64>(e, tp);
    merge_levelp<128>(e, tp);
    merge_levelp<256>(e, tp);
    merge_levelp<512>(e, tp);
    merge_levelp<1024>(e, tp);

    // k = 2048: first pass lm = 64 crosses the pair's two waves -> LDS (up = true)
    {
        #pragma unroll
        for (int v = 0; v < VV; v++)
            sbu[pbu + (v << 7) + tp] = e[v];
        __syncthreads();
        const int pt = tp ^ 64;
        const bool keepmin = (tp & 64) == 0;
        #pragma unroll
        for (int v = 0; v < VV; v++) {
            u32 pv = sbu[pbu + (v << 7) + pt];
            e[v] = keepmin ? pk_min(e[v], pv) : pk_max(e[v], pv);
        }
    }
    cross_chainp<32>(e, true, tp);             // k = 2048 remainder
    intra16p(e, true);

    // ---- sum of squared diffs: lo half = sorted x-col, hi half = sorted y-col
    float s = 0.f;
    #pragma unroll
    for (int v = 0; v < VV; v++) {
        h2 h = __builtin_bit_cast(h2, e[v]);
        float d = (float)h[0] - (float)h[1];
        s += d * d;
    }
    #pragma unroll
    for (int off = 32; off > 0; off >>= 1)
        s += __shfl_down(s, off, 64);
    if ((tid & 63) == 0)
        atomicAdd(&ws[b * NSTRIPE + (cp & (NSTRIPE - 1))], s);
}

__global__ void finalize_kernel(const float* __restrict__ ws, float* __restrict__ out) {
    __shared__ float red[256];
    int tid = threadIdx.x;
    for (int b = 0; b < BB; b++) {
        float s = 0.f;
        for (int i = tid; i < NSTRIPE; i += 256) s += ws[b * NSTRIPE + i];
        red[tid] = s;
        __syncthreads();
        for (int o = 128; o > 0; o >>= 1) {
            if (tid < o) red[tid] += red[tid + o];
            __syncthreads();
        }
        if (tid == 0) {
            float swd = red[0] / ((float)NN * (float)PP);
            out[b] = expf(-swd * swd * 0.5f);
        }
        __syncthreads();
    }
}

extern "C" void kernel_launch(void* const* d_in, const int* in_sizes, int n_in,
                              void* d_out, int out_size, void* d_ws, size_t ws_size,
                              hipStream_t stream) {
    const float* x = (const float*)d_in[0];
    const float* y = (const float*)d_in[1];
    const float* proj = (const float*)d_in[2];
    float* out = (float*)d_out;
    float* ws = (float*)d_ws;

    zero_ws_kernel<<<(BB * NSTRIPE + 255) / 256, 256, 0, stream>>>(ws);
    swd_kernel<<<BB * PP / 2, 256, 0, stream>>>(x, y, proj, ws);
    finalize_kernel<<<1, 256, 0, stream>>>(ws, out);
}

// Round 10
// 641.875 us; speedup vs baseline: 7.8320x; 1.8276x over previous
//
#include <hip/hip_runtime.h>
#include <math.h>

#define BB 4
#define NN 2048
#define DD 64
#define PP 8192
#define NSTRIPE 512
#define VV 16          // packed elements per lane; 128 threads per column-pair
#define GSTR 2056      // u32 stride between proj columns in LDS (2-way banks max, 16B aligned)

typedef unsigned int u32;
typedef _Float16 h2 __attribute__((ext_vector_type(2)));

__global__ void zero_ws_kernel(float* ws) {
    int t = blockIdx.x * blockDim.x + threadIdx.x;
    if (t < BB * NSTRIPE) ws[t] = 0.f;
}

__device__ __forceinline__ h2 pk2(float a, float b) {
#if __has_builtin(__builtin_amdgcn_cvt_pkrtz)
    return __builtin_bit_cast(h2, __builtin_amdgcn_cvt_pkrtz(a, b));
#else
    h2 r = { (_Float16)a, (_Float16)b };
    return r;
#endif
}

// 2-wide fp16 dot with f32 accumulate -> v_dot2_f32_f16
__device__ __forceinline__ float dot2acc(h2 a, h2 b, float c) {
#if __has_builtin(__builtin_amdgcn_fdot2)
    return __builtin_amdgcn_fdot2(a, b, c, false);
#else
    return c + (float)a[0] * (float)b[0] + (float)a[1] * (float)b[1];
#endif
}

// packed fp16 min/max -> v_pk_min_f16 / v_pk_max_f16
__device__ __forceinline__ u32 pk_min(u32 a, u32 b) {
    h2 r = __builtin_elementwise_min(__builtin_bit_cast(h2, a), __builtin_bit_cast(h2, b));
    return __builtin_bit_cast(u32, r);
}
__device__ __forceinline__ u32 pk_max(u32 a, u32 b) {
    h2 r = __builtin_elementwise_max(__builtin_bit_cast(h2, a), __builtin_bit_cast(h2, b));
    return __builtin_bit_cast(u32, r);
}

// packed CE: both halves (x-col in lo, y-col in hi) sort through the same network
__device__ __forceinline__ void ce2(u32& a, u32& b, bool up) {
    u32 lo = pk_min(a, b), hi = pk_max(a, b);
    a = up ? lo : hi;
    b = up ? hi : lo;
}

// exchange with lane^LM inside a wave64 (verified rounds 3-8):
// LM=1,2 : DPP quad_perm ; LM=8 : DPP row_ror:8 ; LM=4,16 : ds_swizzle xor ; LM=32 : shfl
template<int LM>
__device__ __forceinline__ int xorlane_i(int x) {
    if constexpr (LM == 1)       return __builtin_amdgcn_update_dpp(x, x, 0xB1, 0xF, 0xF, false);
    else if constexpr (LM == 2)  return __builtin_amdgcn_update_dpp(x, x, 0x4E, 0xF, 0xF, false);
    else if constexpr (LM == 4)  return __builtin_amdgcn_ds_swizzle(x, 0x101F);
    else if constexpr (LM == 8)  return __builtin_amdgcn_update_dpp(x, x, 0x128, 0xF, 0xF, false);
    else if constexpr (LM == 16) return __builtin_amdgcn_ds_swizzle(x, 0x401F);
    else                         return __shfl_xor(x, 32, 64);
}
template<int LM>
__device__ __forceinline__ float xorlane_f(float v) {
    return __int_as_float(xorlane_i<LM>(__float_as_int(v)));
}

// k = 2,4,8: fully intra-lane, directions depend on v only (compile-time)
__device__ __forceinline__ void phaseA16p(u32* e) {
    #pragma unroll
    for (int k = 2; k <= 8; k <<= 1)
        #pragma unroll
        for (int j = k >> 1; j >= 1; j >>= 1)
            #pragma unroll
            for (int v = 0; v < VV; v++)
                if ((v & j) == 0) ce2(e[v], e[v | j], (v & k) == 0);
}

// intra-lane tail j = 8,4,2,1 with uniform runtime direction
__device__ __forceinline__ void intra16p(u32* e, bool up) {
    #pragma unroll
    for (int j = 8; j >= 1; j >>= 1)
        #pragma unroll
        for (int v = 0; v < VV; v++)
            if ((v & j) == 0) ce2(e[v], e[v | j], up);
}

template<int LM>
__device__ __forceinline__ void crossp(u32* e, bool keepmin) {
    #pragma unroll
    for (int v = 0; v < VV; v++) {
        u32 p = (u32)xorlane_i<LM>((int)e[v]);
        e[v] = keepmin ? pk_min(e[v], p) : pk_max(e[v], p);
    }
}

template<int LM>
__device__ __forceinline__ void cross_chainp(u32* e, bool up, int tp) {
    crossp<LM>(e, up == ((tp & LM) == 0));
    if constexpr (LM > 1) cross_chainp<(LM >> 1)>(e, up, tp);
}

template<int K>
__device__ __forceinline__ void merge_levelp(u32* e, int tp) {
    const bool up = (tp & (K >> 4)) == 0;
    cross_chainp<(K >> 5)>(e, up, tp);
    intra16p(e, up);
}

__global__ __launch_bounds__(256) void swd_kernel(const float* __restrict__ x,
                                                  const float* __restrict__ y,
                                                  const float* __restrict__ proj,
                                                  float* __restrict__ ws) {
    __shared__ __align__(16) u32 sbu[4 * GSTR];   // ~33 KB: 4 proj columns of 2048 packed

    const int tid = threadIdx.x;
    const int lane = tid & 63;
    const int w = tid >> 6;                    // wave 0..3: rows w*512..w*512+511
    const int r4 = lane >> 2;
    const int c4 = lane & 3;
    const int blk = blockIdx.x;
    const int b = blk >> 11;                   // 2048 blocks per batch
    const int pbase = (blk & 2047) << 2;       // 4 proj rows per block

    // ---- pack this lane's quarter (16 cols spread over the 4 lines) of the 4 proj rows
    h2 pjh[4][8];
    #pragma unroll
    for (int g = 0; g < 4; g++) {
        const float4* pr = (const float4*)(proj + (size_t)(pbase + g) * DD);
        #pragma unroll
        for (int k = 0; k < 4; k++) {
            float4 f = pr[(k << 2) + c4];
            pjh[g][2 * k]     = pk2(f.x, f.y);
            pjh[g][2 * k + 1] = pk2(f.z, f.w);
        }
    }

    // ---- projection: block reads x[b],y[b] exactly once; 4 dots per line read
    const float* xr0 = x + ((size_t)b * NN + (w << 9) + r4) * DD + (c4 << 2);
    const float* yr0 = y + ((size_t)b * NN + (w << 9) + r4) * DD + (c4 << 2);

    #pragma unroll 2
    for (int it = 0; it < 32; it++) {          // 16 rows / wave-iteration
        const float* xi = xr0 + (size_t)it * 16 * DD;
        const float* yi = yr0 + (size_t)it * 16 * DD;
        h2 xh[8], yh[8];
        #pragma unroll
        for (int k = 0; k < 4; k++) {
            float4 f = *(const float4*)(xi + (k << 4));
            xh[2 * k]     = pk2(f.x, f.y);
            xh[2 * k + 1] = pk2(f.z, f.w);
            float4 gq = *(const float4*)(yi + (k << 4));
            yh[2 * k]     = pk2(gq.x, gq.y);
            yh[2 * k + 1] = pk2(gq.z, gq.w);
        }
        float ax[4] = {0.f, 0.f, 0.f, 0.f};
        float ay[4] = {0.f, 0.f, 0.f, 0.f};
        #pragma unroll
        for (int g = 0; g < 4; g++)
            #pragma unroll
            for (int kk = 0; kk < 8; kk++) {
                ax[g] = dot2acc(pjh[g][kk], xh[kk], ax[g]);
                ay[g] = dot2acc(pjh[g][kk], yh[kk], ay[g]);
            }
        // quad butterfly: every lane gets the 4-lane row sums
        #pragma unroll
        for (int g = 0; g < 4; g++) {
            ax[g] += xorlane_f<1>(ax[g]); ax[g] += xorlane_f<2>(ax[g]);
            ay[g] += xorlane_f<1>(ay[g]); ay[g] += xorlane_f<2>(ay[g]);
        }
        // lane c4 keeps projection g=c4 and writes its packed (x,y) value
        float sax = c4 == 0 ? ax[0] : c4 == 1 ? ax[1] : c4 == 2 ? ax[2] : ax[3];
        float say = c4 == 0 ? ay[0] : c4 == 1 ? ay[1] : c4 == 2 ? ay[2] : ay[3];
        const int row = (w << 9) + (it << 4) + r4;
        sbu[c4 * GSTR + row] = __builtin_bit_cast(u32, pk2(sax, say));
    }
    __syncthreads();

    // ---- two sort rounds: half-block h sorts proj g = rnd*2 + h
    const int tp = tid & 127;
    const int half = tid >> 7;

    #pragma unroll 1
    for (int rnd = 0; rnd < 2; rnd++) {
        const int g = (rnd << 1) | half;
        u32* col = sbu + g * GSTR;

        // readback into blocked register layout: element i = tp*16 + v
        u32 e[VV];
        {
            const uint4* s4 = (const uint4*)(col + tp * VV);
            #pragma unroll
            for (int vb = 0; vb < 4; vb++) {
                uint4 t = s4[vb];
                e[vb * 4 + 0] = t.x; e[vb * 4 + 1] = t.y;
                e[vb * 4 + 2] = t.z; e[vb * 4 + 3] = t.w;
            }
        }
        __syncthreads();                       // col region reused for the lm=64 exchange

        // bitonic sort (both arrays at once, packed)
        phaseA16p(e);
        intra16p(e, (tp & 1) == 0);            // k = 16
        merge_levelp<32>(e, tp);
        merge_levelp<64>(e, tp);
        merge_levelp<128>(e, tp);
        merge_levelp<256>(e, tp);
        merge_levelp<512>(e, tp);
        merge_levelp<1024>(e, tp);

        // k = 2048: lm = 64 crosses the pair's two waves -> LDS (up = true)
        #pragma unroll
        for (int v = 0; v < VV; v++)
            col[(v << 7) + tp] = e[v];
        __syncthreads();
        {
            const int pt = tp ^ 64;
            const bool keepmin = (tp & 64) == 0;
            #pragma unroll
            for (int v = 0; v < VV; v++) {
                u32 pv = col[(v << 7) + pt];
                e[v] = keepmin ? pk_min(e[v], pv) : pk_max(e[v], pv);
            }
        }
        cross_chainp<32>(e, true, tp);         // k = 2048 remainder
        intra16p(e, true);

        // sum of squared diffs: lo half = sorted x-col, hi half = sorted y-col
        float s = 0.f;
        #pragma unroll
        for (int v = 0; v < VV; v++) {
            h2 h = __builtin_bit_cast(h2, e[v]);
            float d = (float)h[0] - (float)h[1];
            s += d * d;
        }
        #pragma unroll
        for (int off = 32; off > 0; off >>= 1)
            s += __shfl_down(s, off, 64);
        if ((tid & 63) == 0)
            atomicAdd(&ws[b * NSTRIPE + ((pbase + g) & (NSTRIPE - 1))], s);
    }
}

__global__ void finalize_kernel(const float* __restrict__ ws, float* __restrict__ out) {
    __shared__ float red[256];
    int tid = threadIdx.x;
    for (int b = 0; b < BB; b++) {
        float s = 0.f;
        for (int i = tid; i < NSTRIPE; i += 256) s += ws[b * NSTRIPE + i];
        red[tid] = s;
        __syncthreads();
        for (int o = 128; o > 0; o >>= 1) {
            if (tid < o) red[tid] += red[tid + o];
            __syncthreads();
        }
        if (tid == 0) {
            float swd = red[0] / ((float)NN * (float)PP);
            out[b] = expf(-swd * swd * 0.5f);
        }
        __syncthreads();
    }
}

extern "C" void kernel_launch(void* const* d_in, const int* in_sizes, int n_in,
                              void* d_out, int out_size, void* d_ws, size_t ws_size,
                              hipStream_t stream) {
    const float* x = (const float*)d_in[0];
    const float* y = (const float*)d_in[1];
    const float* proj = (const float*)d_in[2];
    float* out = (float*)d_out;
    float* ws = (float*)d_ws;

    zero_ws_kernel<<<(BB * NSTRIPE + 255) / 256, 256, 0, stream>>>(ws);
    swd_kernel<<<BB * PP / 4, 256, 0, stream>>>(x, y, proj, ws);
    finalize_kernel<<<1, 256, 0, stream>>>(ws, out);
}

// Round 11
// 567.304 us; speedup vs baseline: 8.8615x; 1.1314x over previous
//
#include <hip/hip_runtime.h>
#include <math.h>

#define BB 4
#define NN 2048
#define DD 64
#define PP 8192
#define NSTRIPE 512
#define VV 16          // packed elements per lane; 128 threads per column-pair
#define GSTR 2056      // u32 stride between proj columns in LDS

typedef unsigned int u32;
typedef _Float16 h2 __attribute__((ext_vector_type(2)));

__global__ void zero_ws_kernel(float* ws) {
    int t = blockIdx.x * blockDim.x + threadIdx.x;
    if (t < BB * NSTRIPE) ws[t] = 0.f;
}

__device__ __forceinline__ h2 pk2(float a, float b) {
#if __has_builtin(__builtin_amdgcn_cvt_pkrtz)
    return __builtin_bit_cast(h2, __builtin_amdgcn_cvt_pkrtz(a, b));
#else
    h2 r = { (_Float16)a, (_Float16)b };
    return r;
#endif
}

__device__ __forceinline__ float dot2acc(h2 a, h2 b, float c) {
#if __has_builtin(__builtin_amdgcn_fdot2)
    return __builtin_amdgcn_fdot2(a, b, c, false);
#else
    return c + (float)a[0] * (float)b[0] + (float)a[1] * (float)b[1];
#endif
}

__device__ __forceinline__ u32 pk_min(u32 a, u32 b) {
    h2 r = __builtin_elementwise_min(__builtin_bit_cast(h2, a), __builtin_bit_cast(h2, b));
    return __builtin_bit_cast(u32, r);
}
__device__ __forceinline__ u32 pk_max(u32 a, u32 b) {
    h2 r = __builtin_elementwise_max(__builtin_bit_cast(h2, a), __builtin_bit_cast(h2, b));
    return __builtin_bit_cast(u32, r);
}

// ascending compare-exchange (static direction): a=min, b=max
__device__ __forceinline__ void ceA(u32& a, u32& b) {
    u32 lo = pk_min(a, b), hi = pk_max(a, b);
    a = lo; b = hi;
}

// lane-xor fetch on the LDS pipe. ds_swizzle BitMode: offset = (xor<<10)|0x1F (xor<=31).
// lane-xor 32 / 63 via ds_bpermute with precomputed byte addresses.
template<int LM>
__device__ __forceinline__ u32 lxf(u32 x, int a32, int a63) {
    if constexpr (LM == 32)      return (u32)__builtin_amdgcn_ds_bpermute(a32, (int)x);
    else if constexpr (LM == 63) return (u32)__builtin_amdgcn_ds_bpermute(a63, (int)x);
    else                         return (u32)__builtin_amdgcn_ds_swizzle((int)x, 0x1F | (LM << 10));
}

// quad-group f32 butterfly adds for the projection reduce (DPP, VALU pipe)
__device__ __forceinline__ float qadd(float v) {
    int x = __float_as_int(v);
    int r1 = __builtin_amdgcn_update_dpp(x, x, 0xB1, 0xF, 0xF, false);  // xor 1
    float s = v + __int_as_float(r1);
    int x2 = __float_as_int(s);
    int r2 = __builtin_amdgcn_update_dpp(x2, x2, 0x4E, 0xF, 0xF, false); // xor 2
    return s + __int_as_float(r2);
}

// normalized bitonic sort of the 16 intra-lane elements (all static)
__device__ __forceinline__ void sort16(u32* e) {
    #pragma unroll
    for (int k = 2; k <= 16; k <<= 1) {
        #pragma unroll
        for (int v = 0; v < VV; v++) {
            int pv = v ^ (k - 1);
            if (v < pv) ceA(e[v], e[pv]);
        }
        #pragma unroll
        for (int j = k >> 2; j >= 1; j >>= 1)
            #pragma unroll
            for (int v = 0; v < VV; v++)
                if ((v & j) == 0) ceA(e[v], e[v | j]);
    }
}

// intra-lane cleaners j = 8,4,2,1 (static ascending)
__device__ __forceinline__ void clean8(u32* e) {
    #pragma unroll
    for (int j = 8; j >= 1; j >>= 1)
        #pragma unroll
        for (int v = 0; v < VV; v++)
            if ((v & j) == 0) ceA(e[v], e[v | j]);
}

// aligned cross pass: partner = same elem index, lane ^ LM; keep = (tp & LM)==0
template<int LM>
__device__ __forceinline__ void crossA(u32* e, bool keep, int a32, int a63) {
    #pragma unroll
    for (int v = 0; v < VV; v++) {
        u32 p = lxf<LM>(e[v], a32, a63);
        e[v] = keep ? pk_min(e[v], p) : pk_max(e[v], p);
    }
}

template<int LM>
__device__ __forceinline__ void crossA_chain(u32* e, int tp, int a32, int a63) {
    crossA<LM>(e, (tp & LM) == 0, a32, a63);
    if constexpr (LM > 1) crossA_chain<(LM >> 1)>(e, tp, a32, a63);
}

// reflection cross pass: partner = elem v^15 at lane ^ LM; both fetches before updates
template<int LM>
__device__ __forceinline__ void crossR(u32* e, bool keep, int a32, int a63) {
    #pragma unroll
    for (int v = 0; v < 8; v++) {
        const int w2 = v ^ 15;
        u32 p1 = lxf<LM>(e[w2], a32, a63);
        u32 p2 = lxf<LM>(e[v], a32, a63);
        e[v]  = keep ? pk_min(e[v],  p1) : pk_max(e[v],  p1);
        e[w2] = keep ? pk_min(e[w2], p2) : pk_max(e[w2], p2);
    }
}

// full in-wave merge level K (32..1024): reflection + aligned cleaners + intra cleaners
template<int K>
__device__ __forceinline__ void level(u32* e, int tp, int a32, int a63) {
    crossR<(K >> 4) - 1>(e, (tp & (K >> 5)) == 0, a32, a63);
    if constexpr (K >= 64) crossA_chain<(K >> 6)>(e, tp, a32, a63);
    clean8(e);
}

__global__ __launch_bounds__(256) void swd_kernel(const float* __restrict__ x,
                                                  const float* __restrict__ y,
                                                  const float* __restrict__ proj,
                                                  float* __restrict__ ws) {
    __shared__ __align__(16) u32 sbu[4 * GSTR];   // 4 proj columns of 2048 packed (x,y)

    const int tid = threadIdx.x;
    const int lane = tid & 63;
    const int w = tid >> 6;
    const int r4 = lane >> 2;
    const int c4 = lane & 3;
    const int blk = blockIdx.x;
    const int b = blk >> 11;                   // 2048 blocks per batch
    const int pbase = (blk & 2047) << 2;       // 4 proj rows per block

    // ---- pack this lane's quarter of the 4 proj rows (fp16 pairs)
    h2 pjh[4][8];
    #pragma unroll
    for (int g = 0; g < 4; g++) {
        const float4* pr = (const float4*)(proj + (size_t)(pbase + g) * DD);
        #pragma unroll
        for (int k = 0; k < 4; k++) {
            float4 f = pr[(k << 2) + c4];
            pjh[g][2 * k]     = pk2(f.x, f.y);
            pjh[g][2 * k + 1] = pk2(f.z, f.w);
        }
    }

    // ---- projection: block reads x[b],y[b] exactly once; 4 dots per line read
    const float* xr0 = x + ((size_t)b * NN + (w << 9) + r4) * DD + (c4 << 2);
    const float* yr0 = y + ((size_t)b * NN + (w << 9) + r4) * DD + (c4 << 2);

    #pragma unroll 2
    for (int it = 0; it < 32; it++) {          // 16 rows / wave-iteration
        const float* xi = xr0 + (size_t)it * 16 * DD;
        const float* yi = yr0 + (size_t)it * 16 * DD;
        h2 xh[8], yh[8];
        #pragma unroll
        for (int k = 0; k < 4; k++) {
            float4 f = *(const float4*)(xi + (k << 4));
            xh[2 * k]     = pk2(f.x, f.y);
            xh[2 * k + 1] = pk2(f.z, f.w);
            float4 gq = *(const float4*)(yi + (k << 4));
            yh[2 * k]     = pk2(gq.x, gq.y);
            yh[2 * k + 1] = pk2(gq.z, gq.w);
        }
        float ax[4] = {0.f, 0.f, 0.f, 0.f};
        float ay[4] = {0.f, 0.f, 0.f, 0.f};
        #pragma unroll
        for (int g = 0; g < 4; g++)
            #pragma unroll
            for (int kk = 0; kk < 8; kk++) {
                ax[g] = dot2acc(pjh[g][kk], xh[kk], ax[g]);
                ay[g] = dot2acc(pjh[g][kk], yh[kk], ay[g]);
            }
        #pragma unroll
        for (int g = 0; g < 4; g++) { ax[g] = qadd(ax[g]); ay[g] = qadd(ay[g]); }
        // lane c4 keeps projection g=c4, writes packed (x,y)
        float sax = c4 == 0 ? ax[0] : c4 == 1 ? ax[1] : c4 == 2 ? ax[2] : ax[3];
        float say = c4 == 0 ? ay[0] : c4 == 1 ? ay[1] : c4 == 2 ? ay[2] : ay[3];
        const int row = (w << 9) + (it << 4) + r4;
        sbu[c4 * GSTR + row] = __builtin_bit_cast(u32, pk2(sax, say));
    }
    __syncthreads();

    // ---- two sort rounds: half-block h sorts proj g = rnd*2 + h
    const int tp = tid & 127;
    const int half = tid >> 7;
    const int a32 = (lane ^ 32) << 2;          // bpermute byte addrs
    const int a63 = (lane ^ 63) << 2;

    #pragma unroll 1
    for (int rnd = 0; rnd < 2; rnd++) {
        const int g = (rnd << 1) | half;
        u32* col = sbu + g * GSTR;

        // readback into blocked register layout: element i = tp*16 + v
        u32 e[VV];
        {
            const uint4* s4 = (const uint4*)(col + tp * VV);
            #pragma unroll
            for (int vb = 0; vb < 4; vb++) {
                uint4 t = s4[vb];
                e[vb * 4 + 0] = t.x; e[vb * 4 + 1] = t.y;
                e[vb * 4 + 2] = t.z; e[vb * 4 + 3] = t.w;
            }
        }
        __syncthreads();                       // col reused by the k=2048 exchange below

        // ---- normalized bitonic sort (all CEs ascending, keep-min at lower index)
        sort16(e);                             // k = 2..16
        level<32>(e, tp, a32, a63);
        level<64>(e, tp, a32, a63);
        level<128>(e, tp, a32, a63);
        level<256>(e, tp, a32, a63);
        level<512>(e, tp, a32, a63);
        level<1024>(e, tp, a32, a63);

        // k = 2048: reflection (tp^127, v^15) crosses the two waves -> LDS
        #pragma unroll
        for (int v = 0; v < VV; v++)
            col[(v << 7) + tp] = e[v];
        __syncthreads();
        {
            const int pt = tp ^ 127;
            const bool keep = (tp & 64) == 0;
            #pragma unroll
            for (int v = 0; v < VV; v++) {
                u32 p = col[((v ^ 15) << 7) + pt];
                e[v] = keep ? pk_min(e[v], p) : pk_max(e[v], p);
            }
        }
        crossA_chain<32>(e, tp, a32, a63);     // j = 512..16
        clean8(e);                             // j = 8..1

        // ---- sum of squared diffs: lo half = sorted x-col, hi half = sorted y-col
        float s = 0.f;
        #pragma unroll
        for (int v = 0; v < VV; v++) {
            h2 h = __builtin_bit_cast(h2, e[v]);
            float d = (float)h[0] - (float)h[1];
            s += d * d;
        }
        #pragma unroll
        for (int off = 32; off > 0; off >>= 1)
            s += __shfl_down(s, off, 64);
        if ((tid & 63) == 0)
            atomicAdd(&ws[b * NSTRIPE + ((pbase + g) & (NSTRIPE - 1))], s);
    }
}

__global__ void finalize_kernel(const float* __restrict__ ws, float* __restrict__ out) {
    __shared__ float red[256];
    int tid = threadIdx.x;
    for (int b = 0; b < BB; b++) {
        float s = 0.f;
        for (int i = tid; i < NSTRIPE; i += 256) s += ws[b * NSTRIPE + i];
        red[tid] = s;
        __syncthreads();
        for (int o = 128; o > 0; o >>= 1) {
            if (tid < o) red[tid] += red[tid + o];
            __syncthreads();
        }
        if (tid == 0) {
            float swd = red[0] / ((float)NN * (float)PP);
            out[b] = expf(-swd * swd * 0.5f);
        }
        __syncthreads();
    }
}

extern "C" void kernel_launch(void* const* d_in, const int* in_sizes, int n_in,
                              void* d_out, int out_size, void* d_ws, size_t ws_size,
                              hipStream_t stream) {
    const float* x = (const float*)d_in[0];
    const float* y = (const float*)d_in[1];
    const float* proj = (const float*)d_in[2];
    float* out = (float*)d_out;
    float* ws = (float*)d_ws;

    zero_ws_kernel<<<(BB * NSTRIPE + 255) / 256, 256, 0, stream>>>(ws);
    swd_kernel<<<BB * PP / 4, 256, 0, stream>>>(x, y, proj, ws);
    finalize_kernel<<<1, 256, 0, stream>>>(ws, out);
}